// Round 6
// baseline (238.820 us; speedup 1.0000x reference)
//
#include <hip/hip_runtime.h>
#include <hip/hip_bf16.h>
#include <cstdint>
#include <math.h>

#define B_DIM 32
#define T_DIM 1000
#define D_DIM 768
#define V_DIM 31
#define L_DIM 200
#define S_DIM 401      // 2L+1 CTC states
#define SP 7           // states per lane (64*7 = 448 >= 401)
#define S_PAD 448
#define VSTRIDE 32     // padded prob-row stride: 32 floats = 128 B = 1 cache line
#define CH 8           // chunk (steps); prefetch distance = 8 steps

// Wave-wide shift-up-by-1 via DPP WAVE_SHR1 (0x138): pure VALU. Lane 0 -> 0.
__device__ __forceinline__ float shup1_f(float x) {
    int r = __builtin_amdgcn_update_dpp(0, __float_as_int(x), 0x138, 0xF, 0xF, true);
    return __int_as_float(r);
}
__device__ __forceinline__ int shup1_i(int x) {
    return __builtin_amdgcn_update_dpp(0, x, 0x138, 0xF, 0xF, true);
}

// ---------------------------------------------------------------------------
// Kernel 1: logits = pred @ W^T + b, probs = softmax -> ws (B,T,32), linear.
// pred staged per k-tile into LDS (coalesced HBM reads, no L1 dependence).
// Block 256 = 4 waves; wave w owns rows w*32..w*32+31; lane 32-split covers
// two 32-wide k-halves, merged once at the end via shfl_xor(32).
// ---------------------------------------------------------------------------
__global__ __launch_bounds__(256) void head_softmax_kernel(
    const float* __restrict__ pred,
    const float* __restrict__ W,
    const float* __restrict__ bias,
    float* __restrict__ probs)
{
    __shared__ float predT[128][66];   // stride 66: b64-aligned, 2-way (free) banks
    __shared__ float Wl[V_DIM][64];
    const int tid   = threadIdx.x;
    const int lane  = tid & 63;
    const int w     = tid >> 6;
    const int rbase = blockIdx.x * 128;          // grid = 32000/128 = 250 exactly
    const int rloc  = (w << 5) + (lane & 31);    // block-local row 0..127
    const int khalf = (lane >> 5) & 1;           // which 32-wide k-half

    float acc[V_DIM];
#pragma unroll
    for (int v = 0; v < V_DIM; ++v) acc[v] = 0.f;

    for (int kt = 0; kt < D_DIM; kt += 64) {
        __syncthreads();
        // stage predT[128][64]: 2048 float4-chunks, written as aligned float2 pairs
#pragma unroll
        for (int i = 0; i < 8; ++i) {
            const int idx = i * 256 + tid;       // 0..2047
            const int r   = idx >> 4;
            const int c   = (idx & 15) << 2;
            const float4 v4 = *reinterpret_cast<const float4*>(
                pred + (size_t)(rbase + r) * D_DIM + kt + c);
            *reinterpret_cast<float2*>(&predT[r][c])     = make_float2(v4.x, v4.y);
            *reinterpret_cast<float2*>(&predT[r][c + 2]) = make_float2(v4.z, v4.w);
        }
        // stage Wl[31][64]: 496 float4-chunks
#pragma unroll
        for (int i = 0; i < 2; ++i) {
            const int idx = i * 256 + tid;
            if (idx < 496) {
                const int v = idx >> 4;
                const int c = (idx & 15) << 2;
                *reinterpret_cast<float4*>(&Wl[v][c]) =
                    *reinterpret_cast<const float4*>(W + (size_t)v * D_DIM + kt + c);
            }
        }
        __syncthreads();

        const int kbase = khalf << 5;            // 0 or 32
#pragma unroll
        for (int k = 0; k < 32; k += 4) {
            const float2 x01 = *reinterpret_cast<const float2*>(&predT[rloc][kbase + k]);
            const float2 x23 = *reinterpret_cast<const float2*>(&predT[rloc][kbase + k + 2]);
#pragma unroll
            for (int v = 0; v < V_DIM; ++v) {
                const float4 w4 = *reinterpret_cast<const float4*>(&Wl[v][kbase + k]);
                acc[v] = fmaf(x01.x, w4.x, acc[v]);
                acc[v] = fmaf(x01.y, w4.y, acc[v]);
                acc[v] = fmaf(x23.x, w4.z, acc[v]);
                acc[v] = fmaf(x23.y, w4.w, acc[v]);
            }
        }
    }

    // merge the two k-halves (lanes r and r+32 hold partial sums of same row)
#pragma unroll
    for (int v = 0; v < V_DIM; ++v) acc[v] += __shfl_xor(acc[v], 32);

    // softmax (all lanes compute; halves split the store)
    float m = -1e30f;
#pragma unroll
    for (int v = 0; v < V_DIM; ++v) { acc[v] += bias[v]; m = fmaxf(m, acc[v]); }
    float s = 0.f;
    float e[V_DIM];
#pragma unroll
    for (int v = 0; v < V_DIM; ++v) { e[v] = __expf(acc[v] - m); s += e[v]; }
    const float inv = 1.0f / s;
    float* op = probs + (size_t)(rbase + rloc) * VSTRIDE;
    if (khalf == 0) {
#pragma unroll
        for (int v = 0; v < 16; ++v) op[v] = e[v] * inv;
    } else {
#pragma unroll
        for (int v = 16; v < V_DIM; ++v) op[v] = e[v] * inv;
        op[V_DIM] = 0.f;
    }
}

// ---------------------------------------------------------------------------
// Kernel 2: CTC forward recursion, linear domain, per-lane pow2 scaling.
// DPP neighbor exchange; renorm every 2 steps (exact pow2). CH=8 double
// buffer -> 8-step (~1200 cyc) prefetch distance covers HBM/L3 latency.
// ---------------------------------------------------------------------------
__global__ __launch_bounds__(64, 1) void ctc_alpha_kernel(
    const float* __restrict__ probs,
    const int* __restrict__ targets,
    const int* __restrict__ in_lens,
    const int* __restrict__ tgt_lens,
    float* __restrict__ out_nll)
{
    const int b    = blockIdx.x;
    const int lane = threadIdx.x;
    const int Tin  = in_lens[b];
    const int tl   = tgt_lens[b];
    const int* tgt = targets + b * L_DIM;
    const float* __restrict__ prow = probs + (size_t)b * T_DIM * VSTRIDE;

    int   eoff[SP];
    float m2[SP];
#pragma unroll
    for (int i = 0; i < SP; ++i) {
        const int s = lane * SP + i;
        int e = 0;
        float mm = 0.f;
        if (s < S_DIM && (s & 1)) {
            const int k = (s - 1) >> 1;
            const int lab = tgt[k];
            e = lab;
            if (s >= 3 && lab != tgt[k - 1]) mm = 1.f;
        }
        eoff[i] = e;
        m2[i]   = mm;
    }

    // t=0 init
    float a[SP];
#pragma unroll
    for (int i = 0; i < SP; ++i) a[i] = 0.f;
    if (lane == 0) {
        a[0] = prow[0];
        a[1] = prow[eoff[1]];
    }
    int   z2 = 0;
    float f  = (lane == 0) ? 0.f : 1.0f;

    float pA[CH][SP], pB[CH][SP];

    auto LOAD = [&](float (&pb)[CH][SP], int tbase) {
#pragma unroll
        for (int j = 0; j < CH; ++j) {
            int t = tbase + j;
            if (t > T_DIM - 1) t = T_DIM - 1;   // clamp; values unused past Tin
            const float* r = prow + (size_t)t * VSTRIDE;
#pragma unroll
            for (int i = 0; i < SP; ++i) pb[j][i] = r[eoff[i]];
        }
    };

    auto STEP = [&](const float (&pp)[SP]) {
        const float a6  = shup1_f(a[SP - 1]);   // DPP: lane0 -> 0
        const float a5  = shup1_f(a[SP - 2]);
        const float am1 = a6 * f;
        const float am2 = a5 * f;
        float nw[SP];
        nw[0] = (a[0] + am1  + m2[0] * am2) * pp[0];
        nw[1] = (a[1] + a[0] + m2[1] * am1) * pp[1];
#pragma unroll
        for (int i = 2; i < SP; ++i)
            nw[i] = (a[i] + a[i - 1] + m2[i] * a[i - 2]) * pp[i];
#pragma unroll
        for (int i = 0; i < SP; ++i) a[i] = nw[i];
    };

    auto RENORM = [&]() {
        const float mx = fmaxf(fmaxf(fmaxf(a[0], a[1]), fmaxf(a[2], a[3])),
                               fmaxf(fmaxf(a[4], a[5]), a[6]));
        int e;
        (void)frexpf(mx, &e);                    // mx==0 -> e=0
        const int zc = z2 + e;
        const int zp = shup1_i(zc);              // lane0 -> 0 (unused there)
        z2 = (mx > 0.f) ? zc : ((lane == 0) ? zc : zp);
#pragma unroll
        for (int i = 0; i < SP; ++i) a[i] = ldexpf(a[i], -e);
        int dz = zp - z2;
        if (dz > 126) dz = 126;
        if (dz < -126) dz = -126;
        f = (lane == 0) ? 0.f : ldexpf(1.0f, dz);
    };

    LOAD(pA, 1);
    int tb = 1;
    int cur = 0;
    while (tb + CH <= Tin) {
        if (cur == 0) {
            LOAD(pB, tb + CH);
            STEP(pA[0]); STEP(pA[1]); RENORM();
            STEP(pA[2]); STEP(pA[3]); RENORM();
            STEP(pA[4]); STEP(pA[5]); RENORM();
            STEP(pA[6]); STEP(pA[7]); RENORM();
        } else {
            LOAD(pA, tb + CH);
            STEP(pB[0]); STEP(pB[1]); RENORM();
            STEP(pB[2]); STEP(pB[3]); RENORM();
            STEP(pB[4]); STEP(pB[5]); RENORM();
            STEP(pB[6]); STEP(pB[7]); RENORM();
        }
        tb += CH;
        cur ^= 1;
    }
    // tail: rem <= 7 steps on buf[cur] (already loaded, clamped)
    const int rem = Tin - tb;
    if (cur == 0) {
        if (rem > 0) STEP(pA[0]);
        if (rem > 1) STEP(pA[1]);
        RENORM();
        if (rem > 2) STEP(pA[2]);
        if (rem > 3) STEP(pA[3]);
        RENORM();
        if (rem > 4) STEP(pA[4]);
        if (rem > 5) STEP(pA[5]);
        RENORM();
        if (rem > 6) STEP(pA[6]);
    } else {
        if (rem > 0) STEP(pB[0]);
        if (rem > 1) STEP(pB[1]);
        RENORM();
        if (rem > 2) STEP(pB[2]);
        if (rem > 3) STEP(pB[3]);
        RENORM();
        if (rem > 4) STEP(pB[4]);
        if (rem > 5) STEP(pB[5]);
        RENORM();
        if (rem > 6) STEP(pB[6]);
    }

    // absolute log-alpha: log(a) + z2*ln2
    __shared__ float sal[S_PAD];
    const float zln2 = (float)z2 * 0.69314718055994530942f;
#pragma unroll
    for (int i = 0; i < SP; ++i) sal[lane * SP + i] = __logf(a[i]) + zln2;
    __syncthreads();
    if (lane == 0) {
        const float a0 = sal[2 * tl - 1];
        const float a1 = sal[2 * tl];
        const float m  = fmaxf(a0, a1);
        float nll = -(m + __logf(__expf(a0 - m) + __expf(a1 - m)));
        if (!(nll < 1e29f)) nll = 0.f;           // zero_infinity (inf/NaN too)
        out_nll[b] = nll / (float)tl;
    }
}

// ---------------------------------------------------------------------------
// Kernel 3: deterministic mean over B
// ---------------------------------------------------------------------------
__global__ void finalize_kernel(const float* __restrict__ nll, float* __restrict__ out)
{
    if (threadIdx.x == 0 && blockIdx.x == 0) {
        float s = 0.f;
        for (int i = 0; i < B_DIM; ++i) s += nll[i];
        out[0] = s * (1.0f / (float)B_DIM);
    }
}

extern "C" void kernel_launch(void* const* d_in, const int* in_sizes, int n_in,
                              void* d_out, int out_size, void* d_ws, size_t ws_size,
                              hipStream_t stream)
{
    const float* pred     = (const float*)d_in[0];
    const int*   targets  = (const int*)d_in[1];
    const int*   in_lens  = (const int*)d_in[2];
    const int*   tgt_lens = (const int*)d_in[3];
    const float* W        = (const float*)d_in[4];
    const float* bias     = (const float*)d_in[5];

    float* probs = (float*)d_ws;                                  // 32*1000*32 f32 = 4.1 MB
    float* nll   = probs + (size_t)B_DIM * T_DIM * VSTRIDE;       // 32 f32
    float* out   = (float*)d_out;

    head_softmax_kernel<<<(B_DIM * T_DIM) / 128, 256, 0, stream>>>(pred, W, bias, probs);
    ctc_alpha_kernel<<<B_DIM, 64, 0, stream>>>(probs, targets, in_lens, tgt_lens, nll);
    finalize_kernel<<<1, 64, 0, stream>>>(nll, out);
}